// Round 1
// baseline (167.533 us; speedup 1.0000x reference)
//
#include <hip/hip_runtime.h>
#include <hip/hip_bf16.h>

// Problem: CASREL loss. B=32,S=512,H=1024,R=64 -> scalar fp32 loss.
// Strategy: one fused bf16-MFMA GEMM [16384,1024]x[1024,160(pad of 130)]
// with BCE+masked-sum epilogue. subject@Wo folded into per-batch rowBias.

#define B_  32
#define S_  512
#define H_  1024
#define R_  64
#define M_  (B_ * S_)      // 16384 rows
#define NPAD 160           // 130 valid cols padded to 10*16
#define NVALID 130
#define BK 64
#define BKP 72             // padded LDS k-stride (2-way bank conflicts only)
#define MT 32              // rows per block

typedef __attribute__((ext_vector_type(4))) float  floatx4;
typedef __attribute__((ext_vector_type(8))) short  short8;     // 8 bf16 (4 VGPRs)
typedef __attribute__((ext_vector_type(4))) unsigned short u16x4;
typedef __attribute__((ext_vector_type(8))) unsigned short u16x8;

__device__ __forceinline__ unsigned short f2bf(float f) {
    unsigned int u = __float_as_uint(f);
    u = (u + 0x7FFFu + ((u >> 16) & 1u)) >> 16;   // RNE
    return (unsigned short)u;
}
__device__ __forceinline__ float bf2f(unsigned short h) {
    return __uint_as_float(((unsigned int)h) << 16);
}

// ---- K1: build transposed, padded bf16 weight matrix Wt[NPAD][H] ----
// col n: 0..63 = Wo_h[:,n], 64..127 = Wo_t[:,n-64], 128 = Ws_h, 129 = Ws_t, else 0
__global__ void prep_weights(const float* __restrict__ Wo_h,
                             const float* __restrict__ Wo_t,
                             const float* __restrict__ Ws_h,
                             const float* __restrict__ Ws_t,
                             unsigned short* __restrict__ WtG) {
    int n = blockIdx.x;           // 0..159
    int tid = threadIdx.x;        // 256
    for (int k = tid; k < H_; k += 256) {
        float v;
        if (n < 64)        v = Wo_h[k * R_ + n];
        else if (n < 128)  v = Wo_t[k * R_ + (n - 64)];
        else if (n == 128) v = Ws_h[k];
        else if (n == 129) v = Ws_t[k];
        else               v = 0.0f;
        WtG[n * H_ + k] = f2bf(v);
    }
}

// ---- K2: per-batch subject vector (from one-hot), rowBias[b][n], and msum ----
__global__ __launch_bounds__(256) void subj_kernel(
        const float* __restrict__ ctx, const float* __restrict__ head,
        const float* __restrict__ tail, const float* __restrict__ masks,
        const float* __restrict__ Wo_h, const float* __restrict__ Wo_t,
        const float* __restrict__ bo_h, const float* __restrict__ bo_t,
        const float* __restrict__ bs_h, const float* __restrict__ bs_t,
        float* __restrict__ rowBias, float* __restrict__ accum) {
    int b = blockIdx.x, tid = threadIdx.x;
    __shared__ float subj[H_];
    __shared__ int cnt;
    __shared__ int   sidx[8];
    __shared__ float sw[8];
    if (tid == 0) cnt = 0;
    __syncthreads();
    float msk = 0.0f;
    for (int s = tid; s < S_; s += 256) {
        float w = 0.5f * (head[b * S_ + s] + tail[b * S_ + s]);
        if (w != 0.0f) {
            int i = atomicAdd(&cnt, 1);
            if (i < 8) { sidx[i] = s; sw[i] = w; }
        }
        msk += masks[b * S_ + s];
    }
    for (int o = 32; o > 0; o >>= 1) msk += __shfl_down(msk, o, 64);
    if ((tid & 63) == 0) atomicAdd(&accum[1], msk);
    __syncthreads();
    int nnz = cnt < 8 ? cnt : 8;
    for (int h = tid; h < H_; h += 256) {
        float a = 0.0f;
        for (int i = 0; i < nnz; i++)
            a += sw[i] * ctx[((size_t)b * S_ + sidx[i]) * H_ + h];
        subj[h] = a;
    }
    __syncthreads();
    if (tid < NPAD) {
        float bias = tid < 64  ? bo_h[tid]
                   : tid < 128 ? bo_t[tid - 64]
                   : tid == 128 ? bs_h[0]
                   : tid == 129 ? bs_t[0] : 0.0f;
        float acc2 = 0.0f;
        if (tid < 128) {  // subject only added for object columns
            const float* W = (tid < 64) ? Wo_h : Wo_t;
            int c = tid & 63;
            for (int k = 0; k < H_; k++) acc2 += subj[k] * W[k * R_ + c];
        }
        rowBias[b * NPAD + tid] = bias + acc2;
    }
}

// ---- K3: fused GEMM + BCE + masked reduction ----
__global__ __launch_bounds__(256, 2) void main_kernel(
        const float* __restrict__ ctx, const unsigned short* __restrict__ WtG,
        const float* __restrict__ rowBias, const float* __restrict__ masks,
        const float* __restrict__ ash, const float* __restrict__ ast,
        const float* __restrict__ oh, const float* __restrict__ ot,
        float* __restrict__ accum) {
    __shared__ __align__(16) unsigned short Asm[MT * BKP];    // 4.6 KB
    __shared__ __align__(16) unsigned short Bsm[NPAD * BKP];  // 23 KB
    __shared__ float rbuf[4];

    const int tid = threadIdx.x;
    const int bm = blockIdx.x;          // 0..511
    const int gm0 = bm * MT;            // first global row (32 rows, one batch)
    const int b = gm0 >> 9;             // 512 rows per batch
    const int wave = tid >> 6, lane = tid & 63;
    const int wm = wave & 1;            // row half (16 rows)
    const int wn = wave >> 1;           // col half (80 cols = 5 tiles)
    const int lr = lane & 15, q = lane >> 4;

    // staging maps (hoisted)
    const int ar = tid >> 4, af = tid & 15;          // A: row, float4-chunk
    const int bn = tid >> 3, bf = tid & 7;           // B: col-row, 8-bf16 chunk
    const float* aSrc0 = ctx + (size_t)(gm0 + ar) * H_ + af * 4;
    const unsigned short* bSrc0 = WtG + bn * H_ + bf * 8;
    unsigned short* aDst0 = &Asm[ar * BKP + af * 4];
    unsigned short* bDst0 = &Bsm[bn * BKP + bf * 8];

    // fragment read offsets
    const int aOff = (wm * 16 + lr) * BKP + q * 8;
    const int bOffBase = (wn * 80 + lr) * BKP + q * 8;

    floatx4 acc[5];
#pragma unroll
    for (int t = 0; t < 5; t++) acc[t] = (floatx4){0.f, 0.f, 0.f, 0.f};

    for (int k0 = 0; k0 < H_; k0 += BK) {
        __syncthreads();  // previous iter's reads done before overwrite
        // stage A (32x64 fp32 -> bf16)
#pragma unroll
        for (int ii = 0; ii < 2; ii++) {
            const float4 v = *(const float4*)(aSrc0 + ii * 16 * H_ + k0);
            u16x4 u = { f2bf(v.x), f2bf(v.y), f2bf(v.z), f2bf(v.w) };
            *(u16x4*)(aDst0 + ii * 16 * BKP) = u;
        }
        // stage B (160x64 bf16 copy)
#pragma unroll
        for (int ii = 0; ii < 5; ii++) {
            u16x8 w = *(const u16x8*)(bSrc0 + ii * 32 * H_ + k0);
            *(u16x8*)(bDst0 + ii * 32 * BKP) = w;
        }
        __syncthreads();
        // compute: 2 k-steps of 32
#pragma unroll
        for (int kk = 0; kk < BK; kk += 32) {
            short8 afr = *(const short8*)&Asm[aOff + kk];
#pragma unroll
            for (int t = 0; t < 5; t++) {
                short8 bfr = *(const short8*)&Bsm[bOffBase + t * 16 * BKP + kk];
                acc[t] = __builtin_amdgcn_mfma_f32_16x16x32_bf16(afr, bfr, acc[t], 0, 0, 0);
            }
        }
    }

    // epilogue: logits -> BCE * mask -> sum
    float lsum = 0.0f;
#pragma unroll
    for (int t = 0; t < 5; t++) {
        const int col = wn * 80 + t * 16 + lr;
        if (col < NVALID) {
            const float rb = rowBias[b * NPAD + col];
#pragma unroll
            for (int i = 0; i < 4; i++) {
                const int row = gm0 + wm * 16 + q * 4 + i;
                const float l = acc[t][i] + rb;
                float tgt;
                if (col < 64)        tgt = oh[row * R_ + col];
                else if (col < 128)  tgt = ot[row * R_ + (col - 64)];
                else if (col == 128) tgt = ash[row];
                else                 tgt = ast[row];
                const float mk = masks[row];
                const float bce = fmaxf(l, 0.0f) - l * tgt + log1pf(__expf(-fabsf(l)));
                lsum += bce * mk;
            }
        }
    }
    for (int o = 32; o > 0; o >>= 1) lsum += __shfl_down(lsum, o, 64);
    if (lane == 0) rbuf[wave] = lsum;
    __syncthreads();
    if (tid == 0) atomicAdd(&accum[0], rbuf[0] + rbuf[1] + rbuf[2] + rbuf[3]);
}

// ---- K4: finalize ----
__global__ void finalize_kernel(const float* __restrict__ accum, float* __restrict__ out) {
    out[0] = accum[0] / accum[1];
}

extern "C" void kernel_launch(void* const* d_in, const int* in_sizes, int n_in,
                              void* d_out, int out_size, void* d_ws, size_t ws_size,
                              hipStream_t stream) {
    const float* ctx   = (const float*)d_in[0];
    const float* masks = (const float*)d_in[1];
    const float* ash   = (const float*)d_in[2];
    const float* ast   = (const float*)d_in[3];
    const float* sh    = (const float*)d_in[4];
    const float* st    = (const float*)d_in[5];
    const float* oh    = (const float*)d_in[6];
    const float* ot    = (const float*)d_in[7];
    const float* Ws_h  = (const float*)d_in[8];
    const float* bs_h  = (const float*)d_in[9];
    const float* Ws_t  = (const float*)d_in[10];
    const float* bs_t  = (const float*)d_in[11];
    const float* Wo_h  = (const float*)d_in[12];
    const float* bo_h  = (const float*)d_in[13];
    const float* Wo_t  = (const float*)d_in[14];
    const float* bo_t  = (const float*)d_in[15];
    float* out = (float*)d_out;

    char* ws = (char*)d_ws;
    float* accum   = (float*)(ws + 0);                 // [0]=loss sum, [1]=mask sum
    float* rowBias = (float*)(ws + 256);               // [32][160] fp32
    unsigned short* WtG = (unsigned short*)(ws + 256 + 32 * NPAD * 4); // [160][1024] bf16 (offset 20736, 16B aligned)

    hipMemsetAsync(accum, 0, 8, stream);
    prep_weights<<<NPAD, 256, 0, stream>>>(Wo_h, Wo_t, Ws_h, Ws_t, WtG);
    subj_kernel<<<B_, 256, 0, stream>>>(ctx, sh, st, masks, Wo_h, Wo_t,
                                        bo_h, bo_t, bs_h, bs_t, rowBias, accum);
    main_kernel<<<M_ / MT, 256, 0, stream>>>(ctx, WtG, rowBias, masks,
                                             ash, ast, oh, ot, accum);
    finalize_kernel<<<1, 1, 0, stream>>>(accum, out);
}